// Round 5
// baseline (20293.578 us; speedup 1.0000x reference)
//
#include <hip/hip_runtime.h>
#include <math.h>

// LSTM H=1024, T=2048, IN=5, OUT=9, batch=1 on MI355X.
// 64 persistent WGs x 512 threads = 512 waves. Wave W (= pid*8+w) owns
// h columns {2W, 2W+1} (4 gate rows each). NO intra-WG sync in the loop:
// every wave polls the full h ring itself. Ring atom a carries
// (tag u32 | bf16 h[2a+1] | bf16 h[2a]); slot = 512 atoms = 4 KB; depth 4.
// Lane L polls atoms [8L, 8L+8) — one 64B line — via 8 asm global loads
// (sc0 sc1: bypass L1+local L2; LLC is the cross-XCD coherence point) and
// ONE vmcnt(0). Weights f32 in registers: lane L holds wreg[8 rows][16 cols]
// for columns [16L,16L+16). Reduce = R2's 10-shuffle reduce-scatter.
// Publish = one tagged 8B relaxed-agent store per wave (lane 0).

typedef unsigned int u32;
typedef unsigned long long u64;

constexpr int kH     = 1024;
constexpr int kT     = 2048;
constexpr int kIN    = 5;
constexpr int kOUT   = 9;
constexpr int kNWG   = 64;
constexpr int kBLOCK = 512;
constexpr int kAtoms = 512;   // one per wave; atom a <-> h[2a], h[2a+1]

__device__ __forceinline__ float sigm_(float v) {
  return 1.0f / (1.0f + expf(-v));
}
__device__ __forceinline__ float tanh_(float v) {
  return 1.0f - 2.0f / (expf(2.0f * v) + 1.0f);
}
__device__ __forceinline__ u32 bf16_rne(float f) {
  u32 b = __float_as_uint(f);
  return (b + 0x7FFFu + ((b >> 16) & 1u)) >> 16;
}
__device__ __forceinline__ float lo_f(u32 p) { return __uint_as_float(p << 16); }
__device__ __forceinline__ float hi_f(u32 p) { return __uint_as_float(p & 0xFFFF0000u); }

// 8 x 8B loads of one 64B line, L1/L2-bypassing, single drain.
__device__ __forceinline__ void poll8(const u64* p, u64& a0, u64& a1, u64& a2,
                                      u64& a3, u64& a4, u64& a5, u64& a6,
                                      u64& a7) {
  asm volatile(
      "global_load_dwordx2 %0, %8, off sc0 sc1\n\t"
      "global_load_dwordx2 %1, %8, off offset:8 sc0 sc1\n\t"
      "global_load_dwordx2 %2, %8, off offset:16 sc0 sc1\n\t"
      "global_load_dwordx2 %3, %8, off offset:24 sc0 sc1\n\t"
      "global_load_dwordx2 %4, %8, off offset:32 sc0 sc1\n\t"
      "global_load_dwordx2 %5, %8, off offset:40 sc0 sc1\n\t"
      "global_load_dwordx2 %6, %8, off offset:48 sc0 sc1\n\t"
      "global_load_dwordx2 %7, %8, off offset:56 sc0 sc1\n\t"
      "s_waitcnt vmcnt(0)"
      : "=&v"(a0), "=&v"(a1), "=&v"(a2), "=&v"(a3),
        "=&v"(a4), "=&v"(a5), "=&v"(a6), "=&v"(a7)
      : "v"(p)
      : "memory");
}

__global__ __launch_bounds__(kBLOCK, 2) void lstm_allpoll(
    const float* __restrict__ x,     // [T,1,IN]
    const float* __restrict__ w_ih,  // [4H,IN]
    const float* __restrict__ w_hh,  // [4H,H]
    const float* __restrict__ b_ih,  // [4H]
    const float* __restrict__ b_hh,  // [4H]
    const float* __restrict__ w_out, // [OUT,H]
    const float* __restrict__ b_out, // [OUT]
    float* __restrict__ out,         // [OUT]
    u64* __restrict__ ring) {        // ring[4][kAtoms]
  const int pid  = blockIdx.x;
  const int tid  = threadIdx.x;
  const int w    = tid >> 6;
  const int lane = tid & 63;
  const int W    = pid * 8 + w;     // global wave id = atom index

  __shared__ float x_lds[kT * kIN]; // 40 KiB, broadcast-read only

  for (int i = tid; i < kT * kIN; i += kBLOCK) x_lds[i] = x[i];

  // Rows: r = 0..7 -> gate g = r&3 ([i,f,g,o]), jj = 2W + (r>>2).
  // Lane owns h-columns [16*lane, 16*lane+16).
  const int cb = lane * 16;
  float wreg[8][16];
#pragma unroll
  for (int r = 0; r < 8; ++r) {
    const int grow  = (r & 3) * kH + 2 * W + (r >> 2);
    const float* sp = w_hh + (size_t)grow * kH + cb;
#pragma unroll
    for (int m = 0; m < 16; m += 4) {
      const float4 v4 = *(const float4*)(sp + m);
      wreg[r][m] = v4.x; wreg[r][m + 1] = v4.y;
      wreg[r][m + 2] = v4.z; wreg[r][m + 3] = v4.w;
    }
  }
  // per-lane input row (row rmy = lane&7)
  const int rmy    = lane & 7;
  const int growmy = (rmy & 3) * kH + 2 * W + (rmy >> 2);
  float wihr[kIN];
#pragma unroll
  for (int k = 0; k < kIN; ++k) wihr[k] = w_ih[growmy * kIN + k];
  const float biasr = b_ih[growmy] + b_hh[growmy];

  float cst = 0.0f;
  __syncthreads();  // x_lds ready — only barrier in the kernel

  for (int t = 0; t < kT; ++t) {
    // gx for row rmy — before the wait
    float gx = biasr;
#pragma unroll
    for (int k = 0; k < kIN; ++k) gx = fmaf(wihr[k], x_lds[t * kIN + k], gx);

    // ---- poll h_t: lane L waits for atoms [8L, 8L+8) ----
    const u64* pb = ring + (size_t)(t & 3) * kAtoms + (size_t)lane * 8;
    u64 a0, a1, a2, a3, a4, a5, a6, a7;
    bool ok;
    do {
      poll8(pb, a0, a1, a2, a3, a4, a5, a6, a7);
      ok = ((u32)(a0 >> 32) == (u32)t) & ((u32)(a1 >> 32) == (u32)t) &
           ((u32)(a2 >> 32) == (u32)t) & ((u32)(a3 >> 32) == (u32)t) &
           ((u32)(a4 >> 32) == (u32)t) & ((u32)(a5 >> 32) == (u32)t) &
           ((u32)(a6 >> 32) == (u32)t) & ((u32)(a7 >> 32) == (u32)t);
    } while (!__all(ok));

    // unpack 16 h columns into registers
    float hv[16];
    hv[0]  = lo_f((u32)a0); hv[1]  = hi_f((u32)a0);
    hv[2]  = lo_f((u32)a1); hv[3]  = hi_f((u32)a1);
    hv[4]  = lo_f((u32)a2); hv[5]  = hi_f((u32)a2);
    hv[6]  = lo_f((u32)a3); hv[7]  = hi_f((u32)a3);
    hv[8]  = lo_f((u32)a4); hv[9]  = hi_f((u32)a4);
    hv[10] = lo_f((u32)a5); hv[11] = hi_f((u32)a5);
    hv[12] = lo_f((u32)a6); hv[13] = hi_f((u32)a6);
    hv[14] = lo_f((u32)a7); hv[15] = hi_f((u32)a7);

    // ---- matvec: 8 rows x 16 register-resident columns ----
    float acc[8];
#pragma unroll
    for (int r = 0; r < 8; ++r) acc[r] = 0.0f;
#pragma unroll
    for (int m = 0; m < 16; ++m) {
#pragma unroll
      for (int r = 0; r < 8; ++r) acc[r] = fmaf(wreg[r][m], hv[m], acc[r]);
    }

    // ---- reduce-scatter (R2-proven): row (lane&7) total -> this lane ----
    const int b0 = lane & 1, b1 = (lane >> 1) & 1, b2 = (lane >> 2) & 1;
    float n0, n1, n2, n3, m0, m1, f;
    {
      float k0 = b0 ? acc[1] : acc[0], s0 = b0 ? acc[0] : acc[1];
      float k1 = b0 ? acc[3] : acc[2], s1 = b0 ? acc[2] : acc[3];
      float k2 = b0 ? acc[5] : acc[4], s2 = b0 ? acc[4] : acc[5];
      float k3 = b0 ? acc[7] : acc[6], s3 = b0 ? acc[6] : acc[7];
      n0 = k0 + __shfl_xor(s0, 1);
      n1 = k1 + __shfl_xor(s1, 1);
      n2 = k2 + __shfl_xor(s2, 1);
      n3 = k3 + __shfl_xor(s3, 1);
    }
    {
      float k0 = b1 ? n1 : n0, s0 = b1 ? n0 : n1;
      float k1 = b1 ? n3 : n2, s1 = b1 ? n2 : n3;
      m0 = k0 + __shfl_xor(s0, 2);
      m1 = k1 + __shfl_xor(s1, 2);
    }
    {
      float k0 = b2 ? m1 : m0, s0 = b2 ? m0 : m1;
      f = k0 + __shfl_xor(s0, 4);
    }
    f += __shfl_xor(f, 8);
    f += __shfl_xor(f, 16);
    f += __shfl_xor(f, 32);

    // ---- nonlinearity (gate = lane&3; [i,f,g,o]) ----
    const float gtot = f + gx;
    const int   gate = lane & 3;
    const float u    = (gate == 2) ? 2.0f * gtot : gtot;
    float n = sigm_(u);
    n = (gate == 2) ? (2.0f * n - 1.0f) : n;

    // ---- quad gather + state update (lanes 0-3: j=2W, 4-7: j=2W+1) ----
    const int   qb = lane & ~3;
    const float ni = __shfl(n, qb + 0);
    const float nf = __shfl(n, qb + 1);
    const float ng = __shfl(n, qb + 2);
    const float no = __shfl(n, qb + 3);
    cst = nf * cst + ni * ng;
    const float hval = no * tanh_(cst);

    // ---- publish atom W: (tag t+1 | bf16 h[2W+1] | bf16 h[2W]) ----
    const float h1 = __shfl(hval, 4);
    if (lane == 0) {
      const u64 pack = ((u64)(u32)(t + 1) << 32) |
                       (u64)(bf16_rne(hval) | (bf16_rne(h1) << 16));
      __hip_atomic_store(ring + (size_t)((t + 1) & 3) * kAtoms + W, pack,
                         __ATOMIC_RELAXED, __HIP_MEMORY_SCOPE_AGENT);
    }
  }

  // ---- epilogue: tanh -> 9x1024 matvec -> log_softmax (wave 0 only) ----
  if (W == 0) {
    const u64* pb = ring + (size_t)(kT & 3) * kAtoms + (size_t)lane * 8;
    u64 a0, a1, a2, a3, a4, a5, a6, a7;
    bool ok;
    do {
      poll8(pb, a0, a1, a2, a3, a4, a5, a6, a7);
      ok = ((u32)(a0 >> 32) == (u32)kT) & ((u32)(a1 >> 32) == (u32)kT) &
           ((u32)(a2 >> 32) == (u32)kT) & ((u32)(a3 >> 32) == (u32)kT) &
           ((u32)(a4 >> 32) == (u32)kT) & ((u32)(a5 >> 32) == (u32)kT) &
           ((u32)(a6 >> 32) == (u32)kT) & ((u32)(a7 >> 32) == (u32)kT);
    } while (!__all(ok));

    float z[16];
    z[0]  = tanh_(lo_f((u32)a0)); z[1]  = tanh_(hi_f((u32)a0));
    z[2]  = tanh_(lo_f((u32)a1)); z[3]  = tanh_(hi_f((u32)a1));
    z[4]  = tanh_(lo_f((u32)a2)); z[5]  = tanh_(hi_f((u32)a2));
    z[6]  = tanh_(lo_f((u32)a3)); z[7]  = tanh_(hi_f((u32)a3));
    z[8]  = tanh_(lo_f((u32)a4)); z[9]  = tanh_(hi_f((u32)a4));
    z[10] = tanh_(lo_f((u32)a5)); z[11] = tanh_(hi_f((u32)a5));
    z[12] = tanh_(lo_f((u32)a6)); z[13] = tanh_(hi_f((u32)a6));
    z[14] = tanh_(lo_f((u32)a7)); z[15] = tanh_(hi_f((u32)a7));

    float logits[kOUT];
#pragma unroll
    for (int r = 0; r < kOUT; ++r) {
      const float* wr = w_out + (size_t)r * kH + lane * 16;
      float acc = 0.0f;
#pragma unroll
      for (int i = 0; i < 16; ++i) acc = fmaf(wr[i], z[i], acc);
#pragma unroll
      for (int off = 32; off; off >>= 1) acc += __shfl_xor(acc, off);
      logits[r] = acc + b_out[r];
    }
    if (lane == 0) {
      float m = logits[0];
#pragma unroll
      for (int r = 1; r < kOUT; ++r) m = fmaxf(m, logits[r]);
      float s = 0.0f;
#pragma unroll
      for (int r = 0; r < kOUT; ++r) s += expf(logits[r] - m);
      const float lse = m + logf(s);
#pragma unroll
      for (int r = 0; r < kOUT; ++r) out[r] = logits[r] - lse;
    }
  }
}

extern "C" void kernel_launch(void* const* d_in, const int* in_sizes, int n_in,
                              void* d_out, int out_size, void* d_ws, size_t ws_size,
                              hipStream_t stream) {
  const float* x     = (const float*)d_in[0];
  const float* w_ih  = (const float*)d_in[1];
  const float* w_hh  = (const float*)d_in[2];
  const float* b_ih  = (const float*)d_in[3];
  const float* b_hh  = (const float*)d_in[4];
  const float* w_out = (const float*)d_in[5];
  const float* b_out = (const float*)d_in[6];
  float* out  = (float*)d_out;
  u64*   ring = (u64*)d_ws;

  // Zero all 4 ring slots (slot0 = tag0/h0=0; clear stale tags from prior
  // replay). 16 KiB.
  hipMemsetAsync(d_ws, 0, (size_t)4 * kAtoms * sizeof(u64), stream);

  lstm_allpoll<<<kNWG, kBLOCK, 0, stream>>>(x, w_ih, w_hh, b_ih, b_hh,
                                            w_out, b_out, out, ring);
}

// Round 6
// 6888.353 us; speedup vs baseline: 2.9461x; 2.9461x over previous
//
#include <hip/hip_runtime.h>
#include <math.h>

// LSTM H=1024, T=2048, IN=5, OUT=9, batch=1 on MI355X.
// R2 structure (proven 3.06us/step), minimal-diff changes:
//  - ring atoms are (tag u32 | bf16 h[2a+1] | bf16 h[2a]) -> slot 4KB
//  - wave0 poll = 8 asm global_load_dwordx2 sc0 sc1 + ONE vmcnt(0)
//    (lane-major: lane k polls atoms {k + 64m}, each instr wave-coalesced)
// Everything else is R2 verbatim: 64 WGs x 512 thr; wave w of WG b owns
// h cols {2W, 2W+1}, W = b*8+w; f32 weights in registers wreg[8][16]
// (lane owns cols lane+64k); wave0 detects tag t, fans h out to LDS f32,
// raises hflag; waves 1-7 spin hflag; 10-shuffle reduce-scatter; per-lane
// gates; quad gather; lane0 publishes one tagged 8B relaxed-agent store.

typedef unsigned int u32;
typedef unsigned long long u64;

constexpr int kH     = 1024;
constexpr int kT     = 2048;
constexpr int kIN    = 5;
constexpr int kOUT   = 9;
constexpr int kNWG   = 64;
constexpr int kBLOCK = 512;
constexpr int kAtoms = 512;   // atom a <-> h cols {2a, 2a+1}; slot = 4 KB

__device__ __forceinline__ float sigm_(float v) {
  return 1.0f / (1.0f + expf(-v));
}
__device__ __forceinline__ float tanh_(float v) {
  return 1.0f - 2.0f / (expf(2.0f * v) + 1.0f);
}
__device__ __forceinline__ u32 bf16_rne(float f) {
  u32 b = __float_as_uint(f);
  return (b + 0x7FFFu + ((b >> 16) & 1u)) >> 16;
}
__device__ __forceinline__ float lo_f(u32 p) { return __uint_as_float(p << 16); }
__device__ __forceinline__ float hi_f(u32 p) { return __uint_as_float(p & 0xFFFF0000u); }

// One poll sample: 8 x 8B loads at 512B stride (atoms k, k+64, ..., k+448),
// L1/L2-bypassing (LLC is the cross-XCD coherence point), single drain.
// Each instruction is wave-coalesced: 64 lanes x 8B contiguous = 512B.
__device__ __forceinline__ void poll8(const u64* p, u64& a0, u64& a1, u64& a2,
                                      u64& a3, u64& a4, u64& a5, u64& a6,
                                      u64& a7) {
  asm volatile(
      "global_load_dwordx2 %0, %8, off sc0 sc1\n\t"
      "global_load_dwordx2 %1, %8, off offset:512 sc0 sc1\n\t"
      "global_load_dwordx2 %2, %8, off offset:1024 sc0 sc1\n\t"
      "global_load_dwordx2 %3, %8, off offset:1536 sc0 sc1\n\t"
      "global_load_dwordx2 %4, %8, off offset:2048 sc0 sc1\n\t"
      "global_load_dwordx2 %5, %8, off offset:2560 sc0 sc1\n\t"
      "global_load_dwordx2 %6, %8, off offset:3072 sc0 sc1\n\t"
      "global_load_dwordx2 %7, %8, off offset:3584 sc0 sc1\n\t"
      "s_waitcnt vmcnt(0)"
      : "=&v"(a0), "=&v"(a1), "=&v"(a2), "=&v"(a3),
        "=&v"(a4), "=&v"(a5), "=&v"(a6), "=&v"(a7)
      : "v"(p)
      : "memory");
}

__global__ __launch_bounds__(kBLOCK, 2) void lstm_v6(
    const float* __restrict__ x,     // [T,1,IN]
    const float* __restrict__ w_ih,  // [4H,IN]
    const float* __restrict__ w_hh,  // [4H,H]
    const float* __restrict__ b_ih,  // [4H]
    const float* __restrict__ b_hh,  // [4H]
    const float* __restrict__ w_out, // [OUT,H]
    const float* __restrict__ b_out, // [OUT]
    float* __restrict__ out,         // [OUT]
    u64* __restrict__ ring) {        // ring[4][kAtoms]
  const int pid  = blockIdx.x;
  const int tid  = threadIdx.x;
  const int w    = tid >> 6;
  const int lane = tid & 63;
  const int W    = pid * 8 + w;     // global wave id = atom index

  __shared__ float x_lds[kT * kIN]; // 40 KiB
  __shared__ float h_lds[kH];       // 4 KiB f32
  __shared__ int   hflag;

  for (int i = tid; i < kT * kIN; i += kBLOCK) x_lds[i] = x[i];
  if (tid == 0) hflag = 0;

  // Rows r=0..7: gate g = r&3 ([i,f,g,o]), jj = 2W + (r>>2).
  // Lane owns h-columns {lane + 64k : k=0..15}.
  float wreg[8][16];
#pragma unroll
  for (int r = 0; r < 8; ++r) {
    const int grow  = (r & 3) * kH + 2 * W + (r >> 2);
    const float* sp = w_hh + (size_t)grow * kH + lane;
#pragma unroll
    for (int k = 0; k < 16; ++k) wreg[r][k] = sp[64 * k];
  }
  const int rmy    = lane & 7;
  const int growmy = (rmy & 3) * kH + 2 * W + (rmy >> 2);
  float wihr[kIN];
#pragma unroll
  for (int k = 0; k < kIN; ++k) wihr[k] = w_ih[growmy * kIN + k];
  const float biasr = b_ih[growmy] + b_hh[growmy];

  float cst = 0.0f;
  __syncthreads();  // x_lds + hflag ready — only barrier in the kernel

  for (int t = 0; t < kT; ++t) {
    // gx for row rmy — VALU work before the wait
    float gx = biasr;
#pragma unroll
    for (int k = 0; k < kIN; ++k) gx = fmaf(wihr[k], x_lds[t * kIN + k], gx);

    // ---- acquire h_t ----
    if (w == 0) {
      const u64* pb = ring + (size_t)(t & 3) * kAtoms + lane;
      u64 a0, a1, a2, a3, a4, a5, a6, a7;
      bool ok;
      do {
        poll8(pb, a0, a1, a2, a3, a4, a5, a6, a7);
        ok = ((u32)(a0 >> 32) == (u32)t) & ((u32)(a1 >> 32) == (u32)t) &
             ((u32)(a2 >> 32) == (u32)t) & ((u32)(a3 >> 32) == (u32)t) &
             ((u32)(a4 >> 32) == (u32)t) & ((u32)(a5 >> 32) == (u32)t) &
             ((u32)(a6 >> 32) == (u32)t) & ((u32)(a7 >> 32) == (u32)t);
      } while (!__all(ok));
      // unpack: atom (lane + 64m) -> cols {2*lane + 128m, +1}, f32 pair
      u32 d;
      d = (u32)a0; *(float2*)&h_lds[2 * lane + 0]   = make_float2(lo_f(d), hi_f(d));
      d = (u32)a1; *(float2*)&h_lds[2 * lane + 128] = make_float2(lo_f(d), hi_f(d));
      d = (u32)a2; *(float2*)&h_lds[2 * lane + 256] = make_float2(lo_f(d), hi_f(d));
      d = (u32)a3; *(float2*)&h_lds[2 * lane + 384] = make_float2(lo_f(d), hi_f(d));
      d = (u32)a4; *(float2*)&h_lds[2 * lane + 512] = make_float2(lo_f(d), hi_f(d));
      d = (u32)a5; *(float2*)&h_lds[2 * lane + 640] = make_float2(lo_f(d), hi_f(d));
      d = (u32)a6; *(float2*)&h_lds[2 * lane + 768] = make_float2(lo_f(d), hi_f(d));
      d = (u32)a7; *(float2*)&h_lds[2 * lane + 896] = make_float2(lo_f(d), hi_f(d));
      if (lane == 0)
        __hip_atomic_store(&hflag, t + 1, __ATOMIC_RELEASE,
                           __HIP_MEMORY_SCOPE_WORKGROUP);
    } else {
      while (__hip_atomic_load(&hflag, __ATOMIC_ACQUIRE,
                               __HIP_MEMORY_SCOPE_WORKGROUP) < t + 1) { }
    }

    // ---- matvec: 8 rows x 16 cols per lane (weights in regs, h in LDS) ----
    float acc[8];
#pragma unroll
    for (int r = 0; r < 8; ++r) acc[r] = 0.0f;
#pragma unroll
    for (int k = 0; k < 16; ++k) {
      const float hv = h_lds[lane + 64 * k];
#pragma unroll
      for (int r = 0; r < 8; ++r) acc[r] = fmaf(wreg[r][k], hv, acc[r]);
    }

    // ---- reduce-scatter: row (lane&7) total lands on this lane ----
    const int b0 = lane & 1, b1 = (lane >> 1) & 1, b2 = (lane >> 2) & 1;
    float n0, n1, n2, n3, m0, m1, f;
    {
      float k0 = b0 ? acc[1] : acc[0], s0 = b0 ? acc[0] : acc[1];
      float k1 = b0 ? acc[3] : acc[2], s1 = b0 ? acc[2] : acc[3];
      float k2 = b0 ? acc[5] : acc[4], s2 = b0 ? acc[4] : acc[5];
      float k3 = b0 ? acc[7] : acc[6], s3 = b0 ? acc[6] : acc[7];
      n0 = k0 + __shfl_xor(s0, 1);
      n1 = k1 + __shfl_xor(s1, 1);
      n2 = k2 + __shfl_xor(s2, 1);
      n3 = k3 + __shfl_xor(s3, 1);
    }
    {
      float k0 = b1 ? n1 : n0, s0 = b1 ? n0 : n1;
      float k1 = b1 ? n3 : n2, s1 = b1 ? n2 : n3;
      m0 = k0 + __shfl_xor(s0, 2);
      m1 = k1 + __shfl_xor(s1, 2);
    }
    {
      float k0 = b2 ? m1 : m0, s0 = b2 ? m0 : m1;
      f = k0 + __shfl_xor(s0, 4);
    }
    f += __shfl_xor(f, 8);
    f += __shfl_xor(f, 16);
    f += __shfl_xor(f, 32);

    // ---- nonlinearity (gate = lane&3; [i,f,g,o]) ----
    const float gtot = f + gx;
    const int   gate = lane & 3;
    const float u    = (gate == 2) ? 2.0f * gtot : gtot;
    float n = sigm_(u);
    n = (gate == 2) ? (2.0f * n - 1.0f) : n;

    // ---- quad gather + state update (lanes 0-3: j=2W, 4-7: j=2W+1) ----
    const int   qb = lane & ~3;
    const float ni = __shfl(n, qb + 0);
    const float nf = __shfl(n, qb + 1);
    const float ng = __shfl(n, qb + 2);
    const float no = __shfl(n, qb + 3);
    cst = nf * cst + ni * ng;
    const float hval = no * tanh_(cst);

    // ---- publish atom W: (tag t+1 | bf16 h[2W+1] | bf16 h[2W]) ----
    const float h1 = __shfl(hval, 4);
    if (lane == 0) {
      const u64 pack = ((u64)(u32)(t + 1) << 32) |
                       (u64)(bf16_rne(hval) | (bf16_rne(h1) << 16));
      __hip_atomic_store(ring + (size_t)((t + 1) & 3) * kAtoms + W, pack,
                         __ATOMIC_RELAXED, __HIP_MEMORY_SCOPE_AGENT);
    }
  }

  // ---- epilogue: tanh -> 9x1024 matvec -> log_softmax (wave 0 only) ----
  if (W == 0) {
    const u64* pb = ring + (size_t)(kT & 3) * kAtoms + lane;
    u64 a0, a1, a2, a3, a4, a5, a6, a7;
    bool ok;
    do {
      poll8(pb, a0, a1, a2, a3, a4, a5, a6, a7);
      ok = ((u32)(a0 >> 32) == (u32)kT) & ((u32)(a1 >> 32) == (u32)kT) &
           ((u32)(a2 >> 32) == (u32)kT) & ((u32)(a3 >> 32) == (u32)kT) &
           ((u32)(a4 >> 32) == (u32)kT) & ((u32)(a5 >> 32) == (u32)kT) &
           ((u32)(a6 >> 32) == (u32)kT) & ((u32)(a7 >> 32) == (u32)kT);
    } while (!__all(ok));

    // atom (lane + 64m) -> z cols {2*lane + 128m, +1}
    u64 av[8] = {a0, a1, a2, a3, a4, a5, a6, a7};
    float logits[kOUT];
#pragma unroll
    for (int r = 0; r < kOUT; ++r) logits[r] = 0.0f;
#pragma unroll
    for (int m = 0; m < 8; ++m) {
      const u32 d = (u32)av[m];
      const float z0 = tanh_(lo_f(d));
      const float z1 = tanh_(hi_f(d));
      const int col = 2 * lane + 128 * m;
#pragma unroll
      for (int r = 0; r < kOUT; ++r) {
        const float2 wv = *(const float2*)(w_out + (size_t)r * kH + col);
        logits[r] = fmaf(wv.x, z0, fmaf(wv.y, z1, logits[r]));
      }
    }
#pragma unroll
    for (int r = 0; r < kOUT; ++r) {
#pragma unroll
      for (int off = 32; off; off >>= 1)
        logits[r] += __shfl_xor(logits[r], off);
      logits[r] += b_out[r];
    }
    if (lane == 0) {
      float m = logits[0];
#pragma unroll
      for (int r = 1; r < kOUT; ++r) m = fmaxf(m, logits[r]);
      float s = 0.0f;
#pragma unroll
      for (int r = 0; r < kOUT; ++r) s += expf(logits[r] - m);
      const float lse = m + logf(s);
#pragma unroll
      for (int r = 0; r < kOUT; ++r) out[r] = logits[r] - lse;
    }
  }
}

extern "C" void kernel_launch(void* const* d_in, const int* in_sizes, int n_in,
                              void* d_out, int out_size, void* d_ws, size_t ws_size,
                              hipStream_t stream) {
  const float* x     = (const float*)d_in[0];
  const float* w_ih  = (const float*)d_in[1];
  const float* w_hh  = (const float*)d_in[2];
  const float* b_ih  = (const float*)d_in[3];
  const float* b_hh  = (const float*)d_in[4];
  const float* w_out = (const float*)d_in[5];
  const float* b_out = (const float*)d_in[6];
  float* out  = (float*)d_out;
  u64*   ring = (u64*)d_ws;

  // Zero all 4 ring slots (slot0 must read tag=0 / h=0 at t=0; stale tags
  // from a prior replay must be cleared). 16 KiB.
  hipMemsetAsync(d_ws, 0, (size_t)4 * kAtoms * sizeof(u64), stream);

  lstm_v6<<<kNWG, kBLOCK, 0, stream>>>(x, w_ih, w_hh, b_ih, b_hh,
                                       w_out, b_out, out, ring);
}

// Round 7
// 4360.250 us; speedup vs baseline: 4.6542x; 1.5798x over previous
//
#include <hip/hip_runtime.h>
#include <math.h>

// LSTM H=1024, T=2048, IN=5, OUT=9, batch=1 on MI355X.
// R6 structure with ONE change: single-writer full-line ring stores.
// Each WG's 16 h-columns = 8 atoms (tag u32 | bf16 h[2a+1] | bf16 h[2a])
// = one 64B line. Waves drop their packed pair into an LDS mailbox
// (+ monotonic LDS counter); wave 7 gathers and lanes 0-7 issue ONE
// wave-coalesced 64B store (8 x 8B contiguous, single transaction).
// This kills the 8-partial-stores-per-line RMW/invalidation churn that
// R6's counters exposed (WRITE 4x amplified, FETCH tracking the ring).
// Consumer side (wave0 poll8 -> LDS fanout -> hflag) is R6-verbatim;
// atom a <-> cols {2a, 2a+1} mapping unchanged.

typedef unsigned int u32;
typedef unsigned long long u64;

constexpr int kH     = 1024;
constexpr int kT     = 2048;
constexpr int kIN    = 5;
constexpr int kOUT   = 9;
constexpr int kNWG   = 64;
constexpr int kBLOCK = 512;
constexpr int kAtoms = 512;   // atom a <-> h cols {2a, 2a+1}; slot = 4 KB

__device__ __forceinline__ float sigm_(float v) {
  return 1.0f / (1.0f + expf(-v));
}
__device__ __forceinline__ float tanh_(float v) {
  return 1.0f - 2.0f / (expf(2.0f * v) + 1.0f);
}
__device__ __forceinline__ u32 bf16_rne(float f) {
  u32 b = __float_as_uint(f);
  return (b + 0x7FFFu + ((b >> 16) & 1u)) >> 16;
}
__device__ __forceinline__ float lo_f(u32 p) { return __uint_as_float(p << 16); }
__device__ __forceinline__ float hi_f(u32 p) { return __uint_as_float(p & 0xFFFF0000u); }

// One poll sample: 8 x 8B loads at 512B stride, L1/L2-bypassing, one drain.
// Each instruction is wave-coalesced: 64 lanes x 8B contiguous = 512B.
__device__ __forceinline__ void poll8(const u64* p, u64& a0, u64& a1, u64& a2,
                                      u64& a3, u64& a4, u64& a5, u64& a6,
                                      u64& a7) {
  asm volatile(
      "global_load_dwordx2 %0, %8, off sc0 sc1\n\t"
      "global_load_dwordx2 %1, %8, off offset:512 sc0 sc1\n\t"
      "global_load_dwordx2 %2, %8, off offset:1024 sc0 sc1\n\t"
      "global_load_dwordx2 %3, %8, off offset:1536 sc0 sc1\n\t"
      "global_load_dwordx2 %4, %8, off offset:2048 sc0 sc1\n\t"
      "global_load_dwordx2 %5, %8, off offset:2560 sc0 sc1\n\t"
      "global_load_dwordx2 %6, %8, off offset:3072 sc0 sc1\n\t"
      "global_load_dwordx2 %7, %8, off offset:3584 sc0 sc1\n\t"
      "s_waitcnt vmcnt(0)"
      : "=&v"(a0), "=&v"(a1), "=&v"(a2), "=&v"(a3),
        "=&v"(a4), "=&v"(a5), "=&v"(a6), "=&v"(a7)
      : "v"(p)
      : "memory");
}

__global__ __launch_bounds__(kBLOCK, 2) void lstm_v7(
    const float* __restrict__ x,     // [T,1,IN]
    const float* __restrict__ w_ih,  // [4H,IN]
    const float* __restrict__ w_hh,  // [4H,H]
    const float* __restrict__ b_ih,  // [4H]
    const float* __restrict__ b_hh,  // [4H]
    const float* __restrict__ w_out, // [OUT,H]
    const float* __restrict__ b_out, // [OUT]
    float* __restrict__ out,         // [OUT]
    u64* __restrict__ ring) {        // ring[4][kAtoms]
  const int pid  = blockIdx.x;
  const int tid  = threadIdx.x;
  const int w    = tid >> 6;
  const int lane = tid & 63;
  const int W    = pid * 8 + w;     // global wave id = atom index

  __shared__ float x_lds[kT * kIN]; // 40 KiB
  __shared__ float h_lds[kH];       // 4 KiB f32
  __shared__ u32   mail[8];         // per-wave packed bf16 pair
  __shared__ int   hflag;
  __shared__ int   gcnt;            // monotonic mailbox counter

  for (int i = tid; i < kT * kIN; i += kBLOCK) x_lds[i] = x[i];
  if (tid == 0) { hflag = 0; gcnt = 0; }

  // Rows r=0..7: gate g = r&3 ([i,f,g,o]), jj = 2W + (r>>2).
  // Lane owns h-columns {lane + 64k : k=0..15}.
  float wreg[8][16];
#pragma unroll
  for (int r = 0; r < 8; ++r) {
    const int grow  = (r & 3) * kH + 2 * W + (r >> 2);
    const float* sp = w_hh + (size_t)grow * kH + lane;
#pragma unroll
    for (int k = 0; k < 16; ++k) wreg[r][k] = sp[64 * k];
  }
  const int rmy    = lane & 7;
  const int growmy = (rmy & 3) * kH + 2 * W + (rmy >> 2);
  float wihr[kIN];
#pragma unroll
  for (int k = 0; k < kIN; ++k) wihr[k] = w_ih[growmy * kIN + k];
  const float biasr = b_ih[growmy] + b_hh[growmy];

  float cst = 0.0f;
  __syncthreads();  // x_lds + hflag + gcnt ready — only barrier

  for (int t = 0; t < kT; ++t) {
    // gx for row rmy — VALU work before the wait
    float gx = biasr;
#pragma unroll
    for (int k = 0; k < kIN; ++k) gx = fmaf(wihr[k], x_lds[t * kIN + k], gx);

    // ---- acquire h_t ----
    if (w == 0) {
      const u64* pb = ring + (size_t)(t & 3) * kAtoms + lane;
      u64 a0, a1, a2, a3, a4, a5, a6, a7;
      bool ok;
      do {
        poll8(pb, a0, a1, a2, a3, a4, a5, a6, a7);
        ok = ((u32)(a0 >> 32) == (u32)t) & ((u32)(a1 >> 32) == (u32)t) &
             ((u32)(a2 >> 32) == (u32)t) & ((u32)(a3 >> 32) == (u32)t) &
             ((u32)(a4 >> 32) == (u32)t) & ((u32)(a5 >> 32) == (u32)t) &
             ((u32)(a6 >> 32) == (u32)t) & ((u32)(a7 >> 32) == (u32)t);
      } while (!__all(ok));
      // unpack: atom (lane + 64m) -> cols {2*lane + 128m, +1}, f32 pair
      u32 d;
      d = (u32)a0; *(float2*)&h_lds[2 * lane + 0]   = make_float2(lo_f(d), hi_f(d));
      d = (u32)a1; *(float2*)&h_lds[2 * lane + 128] = make_float2(lo_f(d), hi_f(d));
      d = (u32)a2; *(float2*)&h_lds[2 * lane + 256] = make_float2(lo_f(d), hi_f(d));
      d = (u32)a3; *(float2*)&h_lds[2 * lane + 384] = make_float2(lo_f(d), hi_f(d));
      d = (u32)a4; *(float2*)&h_lds[2 * lane + 512] = make_float2(lo_f(d), hi_f(d));
      d = (u32)a5; *(float2*)&h_lds[2 * lane + 640] = make_float2(lo_f(d), hi_f(d));
      d = (u32)a6; *(float2*)&h_lds[2 * lane + 768] = make_float2(lo_f(d), hi_f(d));
      d = (u32)a7; *(float2*)&h_lds[2 * lane + 896] = make_float2(lo_f(d), hi_f(d));
      if (lane == 0)
        __hip_atomic_store(&hflag, t + 1, __ATOMIC_RELEASE,
                           __HIP_MEMORY_SCOPE_WORKGROUP);
    } else {
      while (__hip_atomic_load(&hflag, __ATOMIC_ACQUIRE,
                               __HIP_MEMORY_SCOPE_WORKGROUP) < t + 1) { }
    }

    // ---- matvec: 8 rows x 16 cols per lane (weights in regs, h in LDS) ----
    float acc[8];
#pragma unroll
    for (int r = 0; r < 8; ++r) acc[r] = 0.0f;
#pragma unroll
    for (int k = 0; k < 16; ++k) {
      const float hv = h_lds[lane + 64 * k];
#pragma unroll
      for (int r = 0; r < 8; ++r) acc[r] = fmaf(wreg[r][k], hv, acc[r]);
    }

    // ---- reduce-scatter: row (lane&7) total lands on this lane ----
    const int b0 = lane & 1, b1 = (lane >> 1) & 1, b2 = (lane >> 2) & 1;
    float n0, n1, n2, n3, m0, m1, f;
    {
      float k0 = b0 ? acc[1] : acc[0], s0 = b0 ? acc[0] : acc[1];
      float k1 = b0 ? acc[3] : acc[2], s1 = b0 ? acc[2] : acc[3];
      float k2 = b0 ? acc[5] : acc[4], s2 = b0 ? acc[4] : acc[5];
      float k3 = b0 ? acc[7] : acc[6], s3 = b0 ? acc[6] : acc[7];
      n0 = k0 + __shfl_xor(s0, 1);
      n1 = k1 + __shfl_xor(s1, 1);
      n2 = k2 + __shfl_xor(s2, 1);
      n3 = k3 + __shfl_xor(s3, 1);
    }
    {
      float k0 = b1 ? n1 : n0, s0 = b1 ? n0 : n1;
      float k1 = b1 ? n3 : n2, s1 = b1 ? n2 : n3;
      m0 = k0 + __shfl_xor(s0, 2);
      m1 = k1 + __shfl_xor(s1, 2);
    }
    {
      float k0 = b2 ? m1 : m0, s0 = b2 ? m0 : m1;
      f = k0 + __shfl_xor(s0, 4);
    }
    f += __shfl_xor(f, 8);
    f += __shfl_xor(f, 16);
    f += __shfl_xor(f, 32);

    // ---- nonlinearity (gate = lane&3; [i,f,g,o]) ----
    const float gtot = f + gx;
    const int   gate = lane & 3;
    const float u    = (gate == 2) ? 2.0f * gtot : gtot;
    float n = sigm_(u);
    n = (gate == 2) ? (2.0f * n - 1.0f) : n;

    // ---- quad gather + state update (lanes 0-3: j=2W, 4-7: j=2W+1) ----
    const int   qb = lane & ~3;
    const float ni = __shfl(n, qb + 0);
    const float nf = __shfl(n, qb + 1);
    const float ng = __shfl(n, qb + 2);
    const float no = __shfl(n, qb + 3);
    cst = nf * cst + ni * ng;
    const float hval = no * tanh_(cst);

    // ---- mailbox: every wave drops its packed pair, bumps counter ----
    const float h1 = __shfl(hval, 4);
    const u32 pair = bf16_rne(hval) | (bf16_rne(h1) << 16);
    if (lane == 0) {
      __hip_atomic_store(&mail[w], pair, __ATOMIC_RELAXED,
                         __HIP_MEMORY_SCOPE_WORKGROUP);
      __hip_atomic_fetch_add(&gcnt, 1, __ATOMIC_RELEASE,
                             __HIP_MEMORY_SCOPE_WORKGROUP);
    }

    // ---- wave 7: gather + ONE full-line (64B) coalesced store ----
    if (w == 7) {
      while (__hip_atomic_load(&gcnt, __ATOMIC_ACQUIRE,
                               __HIP_MEMORY_SCOPE_WORKGROUP) < 8 * (t + 1)) { }
      if (lane < 8) {
        const u32 p = __hip_atomic_load(&mail[lane], __ATOMIC_RELAXED,
                                        __HIP_MEMORY_SCOPE_WORKGROUP);
        const u64 atom = ((u64)(u32)(t + 1) << 32) | (u64)p;
        // lanes 0-7: 8 x 8B contiguous = one 64B line, one transaction
        __hip_atomic_store(ring + (size_t)((t + 1) & 3) * kAtoms + pid * 8 + lane,
                           atom, __ATOMIC_RELAXED, __HIP_MEMORY_SCOPE_AGENT);
      }
    }
  }

  // ---- epilogue: tanh -> 9x1024 matvec -> log_softmax (wave 0 only) ----
  if (W == 0) {
    const u64* pb = ring + (size_t)(kT & 3) * kAtoms + lane;
    u64 a0, a1, a2, a3, a4, a5, a6, a7;
    bool ok;
    do {
      poll8(pb, a0, a1, a2, a3, a4, a5, a6, a7);
      ok = ((u32)(a0 >> 32) == (u32)kT) & ((u32)(a1 >> 32) == (u32)kT) &
           ((u32)(a2 >> 32) == (u32)kT) & ((u32)(a3 >> 32) == (u32)kT) &
           ((u32)(a4 >> 32) == (u32)kT) & ((u32)(a5 >> 32) == (u32)kT) &
           ((u32)(a6 >> 32) == (u32)kT) & ((u32)(a7 >> 32) == (u32)kT);
    } while (!__all(ok));

    // atom (lane + 64m) -> z cols {2*lane + 128m, +1}
    u64 av[8] = {a0, a1, a2, a3, a4, a5, a6, a7};
    float logits[kOUT];
#pragma unroll
    for (int r = 0; r < kOUT; ++r) logits[r] = 0.0f;
#pragma unroll
    for (int m = 0; m < 8; ++m) {
      const u32 d = (u32)av[m];
      const float z0 = tanh_(lo_f(d));
      const float z1 = tanh_(hi_f(d));
      const int col = 2 * lane + 128 * m;
#pragma unroll
      for (int r = 0; r < kOUT; ++r) {
        const float2 wv = *(const float2*)(w_out + (size_t)r * kH + col);
        logits[r] = fmaf(wv.x, z0, fmaf(wv.y, z1, logits[r]));
      }
    }
#pragma unroll
    for (int r = 0; r < kOUT; ++r) {
#pragma unroll
      for (int off = 32; off; off >>= 1)
        logits[r] += __shfl_xor(logits[r], off);
      logits[r] += b_out[r];
    }
    if (lane == 0) {
      float m = logits[0];
#pragma unroll
      for (int r = 1; r < kOUT; ++r) m = fmaxf(m, logits[r]);
      float s = 0.0f;
#pragma unroll
      for (int r = 0; r < kOUT; ++r) s += expf(logits[r] - m);
      const float lse = m + logf(s);
#pragma unroll
      for (int r = 0; r < kOUT; ++r) out[r] = logits[r] - lse;
    }
  }
}

extern "C" void kernel_launch(void* const* d_in, const int* in_sizes, int n_in,
                              void* d_out, int out_size, void* d_ws, size_t ws_size,
                              hipStream_t stream) {
  const float* x     = (const float*)d_in[0];
  const float* w_ih  = (const float*)d_in[1];
  const float* w_hh  = (const float*)d_in[2];
  const float* b_ih  = (const float*)d_in[3];
  const float* b_hh  = (const float*)d_in[4];
  const float* w_out = (const float*)d_in[5];
  const float* b_out = (const float*)d_in[6];
  float* out  = (float*)d_out;
  u64*   ring = (u64*)d_ws;

  // Zero all 4 ring slots (slot0 must read tag=0 / h=0 at t=0; stale tags
  // from a prior replay must be cleared). 16 KiB.
  hipMemsetAsync(d_ws, 0, (size_t)4 * kAtoms * sizeof(u64), stream);

  lstm_v7<<<kNWG, kBLOCK, 0, stream>>>(x, w_ih, w_hh, b_ih, b_hh,
                                       w_out, b_out, out, ring);
}

// Round 8
// 3771.423 us; speedup vs baseline: 5.3809x; 1.1561x over previous
//
#include <hip/hip_runtime.h>
#include <math.h>

// LSTM H=1024, T=2048, IN=5, OUT=9, batch=1 on MI355X.
// R7 transport (tagged bf16-pair atoms, depth-4 ring, single full-line
// publish per WG) with a column-sliced matvec that removes the fanout
// and mailbox hops:
//  - wave w of each WG polls ONLY atoms [64w, 64w+64) = its 512B slice,
//    one coalesced 8B/lane load per sample; unpacks to its own LDS segment.
//  - lane l owns gate-row l (g = l>>4, j = l&15) over cols [128w,128w+128):
//    128 reg-resident FMAs, NO intra-wave reduce.
//  - waves 0-6 store 64 partials to pacc[t&1][w] + release-bump gcnt;
//    wave 7 (fixed finisher, cst in regs) spins gcnt, sums 7+own partials,
//    + gx, gates per-lane, 6 shuffles, publishes one 64B line (lanes 0-7).
// pacc double-buffer is safe: a wave reaches step t+2 only after all WGs
// published t+2, which requires this WG's wave7 to have consumed pacc[t&1].

typedef unsigned int u32;
typedef unsigned long long u64;

constexpr int kH     = 1024;
constexpr int kT     = 2048;
constexpr int kIN    = 5;
constexpr int kOUT   = 9;
constexpr int kNWG   = 64;
constexpr int kBLOCK = 512;
constexpr int kAtoms = 512;   // atom a <-> h cols {2a, 2a+1}; slot = 4 KB

__device__ __forceinline__ float sigm_(float v) {
  return 1.0f / (1.0f + expf(-v));
}
__device__ __forceinline__ float tanh_(float v) {
  return 1.0f - 2.0f / (expf(2.0f * v) + 1.0f);
}
__device__ __forceinline__ u32 bf16_rne(float f) {
  u32 b = __float_as_uint(f);
  return (b + 0x7FFFu + ((b >> 16) & 1u)) >> 16;
}
__device__ __forceinline__ float lo_f(u32 p) { return __uint_as_float(p << 16); }
__device__ __forceinline__ float hi_f(u32 p) { return __uint_as_float(p & 0xFFFF0000u); }

// One-atom poll sample: 8B/lane, wave-coalesced 512B, LLC-coherent.
__device__ __forceinline__ u64 poll1(const u64* p) {
  u64 a;
  asm volatile(
      "global_load_dwordx2 %0, %1, off sc0 sc1\n\t"
      "s_waitcnt vmcnt(0)"
      : "=v"(a) : "v"(p) : "memory");
  return a;
}

// Epilogue-only: 8 x 8B at 512B stride (atoms lane + 64m), one drain.
__device__ __forceinline__ void poll8(const u64* p, u64& a0, u64& a1, u64& a2,
                                      u64& a3, u64& a4, u64& a5, u64& a6,
                                      u64& a7) {
  asm volatile(
      "global_load_dwordx2 %0, %8, off sc0 sc1\n\t"
      "global_load_dwordx2 %1, %8, off offset:512 sc0 sc1\n\t"
      "global_load_dwordx2 %2, %8, off offset:1024 sc0 sc1\n\t"
      "global_load_dwordx2 %3, %8, off offset:1536 sc0 sc1\n\t"
      "global_load_dwordx2 %4, %8, off offset:2048 sc0 sc1\n\t"
      "global_load_dwordx2 %5, %8, off offset:2560 sc0 sc1\n\t"
      "global_load_dwordx2 %6, %8, off offset:3072 sc0 sc1\n\t"
      "global_load_dwordx2 %7, %8, off offset:3584 sc0 sc1\n\t"
      "s_waitcnt vmcnt(0)"
      : "=&v"(a0), "=&v"(a1), "=&v"(a2), "=&v"(a3),
        "=&v"(a4), "=&v"(a5), "=&v"(a6), "=&v"(a7)
      : "v"(p)
      : "memory");
}

__global__ __launch_bounds__(kBLOCK, 2) void lstm_v8(
    const float* __restrict__ x,     // [T,1,IN]
    const float* __restrict__ w_ih,  // [4H,IN]
    const float* __restrict__ w_hh,  // [4H,H]
    const float* __restrict__ b_ih,  // [4H]
    const float* __restrict__ b_hh,  // [4H]
    const float* __restrict__ w_out, // [OUT,H]
    const float* __restrict__ b_out, // [OUT]
    float* __restrict__ out,         // [OUT]
    u64* __restrict__ ring) {        // ring[4][kAtoms]
  const int pid  = blockIdx.x;
  const int tid  = threadIdx.x;
  const int w    = tid >> 6;
  const int lane = tid & 63;

  __shared__ float x_lds[kT * kIN];    // 40 KiB
  __shared__ float h_lds[kH];          // 4 KiB; wave w owns [128w,128w+128)
  __shared__ float pacc[2][7][64];     // partials from waves 0-6, dbuf by t&1
  __shared__ int   gcnt;               // monotonic: waves 0-6 bump per step

  for (int i = tid; i < kT * kIN; i += kBLOCK) x_lds[i] = x[i];
  if (tid == 0) gcnt = 0;

  // Lane l owns gate-row l of this WG: gate g = l>>4 ([i,f,g,o]), j = l&15.
  const int grow = (lane >> 4) * kH + pid * 16 + (lane & 15);
  const int cb   = 128 * w;  // this wave's h-column slice base

  // 128 f32 recurrent weights (row grow, cols [cb, cb+128)) in registers.
  float wreg[128];
  {
    const float* sp = w_hh + (size_t)grow * kH + cb;
#pragma unroll
    for (int m = 0; m < 128; m += 4) {
      const float4 v4 = *(const float4*)(sp + m);
      wreg[m] = v4.x; wreg[m + 1] = v4.y; wreg[m + 2] = v4.z; wreg[m + 3] = v4.w;
    }
  }
  float wihr[kIN];
#pragma unroll
  for (int k = 0; k < kIN; ++k) wihr[k] = w_ih[grow * kIN + k];
  const float biasr = b_ih[grow] + b_hh[grow];

  float cst = 0.0f;  // wave7: cell state for j = lane&15 (4 dup lanes)
  __syncthreads();   // x_lds + gcnt ready — only barrier in the kernel

  for (int t = 0; t < kT; ++t) {
    // gx for row `lane` (used by wave7's finish) — before the wait
    float gx = biasr;
#pragma unroll
    for (int k = 0; k < kIN; ++k) gx = fmaf(wihr[k], x_lds[t * kIN + k], gx);

    // ---- poll own slice: atom 64w+lane (producers = WGs 8w..8w+7) ----
    const u64* pb = ring + (size_t)(t & 3) * kAtoms + 64 * w + lane;
    u64 a;
    do {
      a = poll1(pb);
    } while (!__all((u32)(a >> 32) == (u32)t));

    // unpack into this wave's private h segment: atom -> cols {cb+2l, +1}
    const u32 d = (u32)a;
    *(float2*)&h_lds[cb + 2 * lane] = make_float2(lo_f(d), hi_f(d));

    // ---- partial matvec: row `lane` x cols [cb, cb+128) ----
    float acc0 = 0.0f, acc1 = 0.0f, acc2 = 0.0f, acc3 = 0.0f;
#pragma unroll
    for (int m = 0; m < 128; m += 4) {
      acc0 = fmaf(wreg[m + 0], h_lds[cb + m + 0], acc0);
      acc1 = fmaf(wreg[m + 1], h_lds[cb + m + 1], acc1);
      acc2 = fmaf(wreg[m + 2], h_lds[cb + m + 2], acc2);
      acc3 = fmaf(wreg[m + 3], h_lds[cb + m + 3], acc3);
    }
    const float part = (acc0 + acc1) + (acc2 + acc3);

    if (w < 7) {
      // drop partial, release-bump the counter; immediately proceed to t+1
      pacc[t & 1][w][lane] = part;
      if (lane == 0)
        __hip_atomic_fetch_add(&gcnt, 1, __ATOMIC_RELEASE,
                               __HIP_MEMORY_SCOPE_WORKGROUP);
    } else {
      // ---- finisher: wait for 7 partials of THIS step ----
      while (__hip_atomic_load(&gcnt, __ATOMIC_ACQUIRE,
                               __HIP_MEMORY_SCOPE_WORKGROUP) < 7 * (t + 1)) { }
      float gtot = part + gx;
#pragma unroll
      for (int w2 = 0; w2 < 7; ++w2) gtot += pacc[t & 1][w2][lane];

      // nonlinearity: gate g = lane>>4 ([i,f,g,o]); g -> tanh
      const int gate = lane >> 4;
      const float u = (gate == 2) ? 2.0f * gtot : gtot;
      float n = sigm_(u);
      n = (gate == 2) ? (2.0f * n - 1.0f) : n;

      // gather the 4 gates of j = lane&15
      const int j = lane & 15;
      const float ni = __shfl(n, j);
      const float nf = __shfl(n, 16 + j);
      const float ng = __shfl(n, 32 + j);
      const float no = __shfl(n, 48 + j);
      cst = nf * cst + ni * ng;
      const float hval = no * tanh_(cst);

      // pack pairs and publish ONE 64B line (lanes 0-7)
      const float ph0 = __shfl(hval, 2 * lane);      // j = 2*lane
      const float ph1 = __shfl(hval, 2 * lane + 1);  // j = 2*lane+1
      if (lane < 8) {
        const u64 atom = ((u64)(u32)(t + 1) << 32) |
                         (u64)(bf16_rne(ph0) | (bf16_rne(ph1) << 16));
        __hip_atomic_store(ring + (size_t)((t + 1) & 3) * kAtoms + pid * 8 + lane,
                           atom, __ATOMIC_RELAXED, __HIP_MEMORY_SCOPE_AGENT);
      }
    }
  }

  // ---- epilogue: tanh -> 9x1024 matvec -> log_softmax (WG0 wave0) ----
  if (pid == 0 && w == 0) {
    const u64* pb = ring + (size_t)(kT & 3) * kAtoms + lane;
    u64 a0, a1, a2, a3, a4, a5, a6, a7;
    bool ok;
    do {
      poll8(pb, a0, a1, a2, a3, a4, a5, a6, a7);
      ok = ((u32)(a0 >> 32) == (u32)kT) & ((u32)(a1 >> 32) == (u32)kT) &
           ((u32)(a2 >> 32) == (u32)kT) & ((u32)(a3 >> 32) == (u32)kT) &
           ((u32)(a4 >> 32) == (u32)kT) & ((u32)(a5 >> 32) == (u32)kT) &
           ((u32)(a6 >> 32) == (u32)kT) & ((u32)(a7 >> 32) == (u32)kT);
    } while (!__all(ok));

    // atom (lane + 64m) -> z cols {2*lane + 128m, +1}
    u64 av[8] = {a0, a1, a2, a3, a4, a5, a6, a7};
    float logits[kOUT];
#pragma unroll
    for (int r = 0; r < kOUT; ++r) logits[r] = 0.0f;
#pragma unroll
    for (int m = 0; m < 8; ++m) {
      const u32 d = (u32)av[m];
      const float z0 = tanh_(lo_f(d));
      const float z1 = tanh_(hi_f(d));
      const int col = 2 * lane + 128 * m;
#pragma unroll
      for (int r = 0; r < kOUT; ++r) {
        const float2 wv = *(const float2*)(w_out + (size_t)r * kH + col);
        logits[r] = fmaf(wv.x, z0, fmaf(wv.y, z1, logits[r]));
      }
    }
#pragma unroll
    for (int r = 0; r < kOUT; ++r) {
#pragma unroll
      for (int off = 32; off; off >>= 1)
        logits[r] += __shfl_xor(logits[r], off);
      logits[r] += b_out[r];
    }
    if (lane == 0) {
      float m = logits[0];
#pragma unroll
      for (int r = 1; r < kOUT; ++r) m = fmaxf(m, logits[r]);
      float s = 0.0f;
#pragma unroll
      for (int r = 0; r < kOUT; ++r) s += expf(logits[r] - m);
      const float lse = m + logf(s);
#pragma unroll
      for (int r = 0; r < kOUT; ++r) out[r] = logits[r] - lse;
    }
  }
}

extern "C" void kernel_launch(void* const* d_in, const int* in_sizes, int n_in,
                              void* d_out, int out_size, void* d_ws, size_t ws_size,
                              hipStream_t stream) {
  const float* x     = (const float*)d_in[0];
  const float* w_ih  = (const float*)d_in[1];
  const float* w_hh  = (const float*)d_in[2];
  const float* b_ih  = (const float*)d_in[3];
  const float* b_hh  = (const float*)d_in[4];
  const float* w_out = (const float*)d_in[5];
  const float* b_out = (const float*)d_in[6];
  float* out  = (float*)d_out;
  u64*   ring = (u64*)d_ws;

  // Zero all 4 ring slots (slot0 must read tag=0 / h=0 at t=0; stale tags
  // from a prior replay must be cleared). 16 KiB.
  hipMemsetAsync(d_ws, 0, (size_t)4 * kAtoms * sizeof(u64), stream);

  lstm_v8<<<kNWG, kBLOCK, 0, stream>>>(x, w_ih, w_hh, b_ih, b_hh,
                                       w_out, b_out, out, ring);
}

// Round 9
// 3753.124 us; speedup vs baseline: 5.4071x; 1.0049x over previous
//
#include <hip/hip_runtime.h>
#include <math.h>

// LSTM H=1024, T=2048, IN=5, OUT=9, batch=1 on MI355X.
// R8 structure + REPLICATED ring to cut same-line poll concurrency:
//   ring[slot 0..3][replica 0..R-1][512 atoms]; atom = (tag u32 | 2x bf16).
//   Consumer WG c polls replica (c & (R-1)) only -> 64/R readers per line.
//   Producer wave7 writes ALL replicas with ONE wave store: lane k writes
//   replica k>>3, atom (pid*8 + (k&7)) -> 8 disjoint full 64B lines,
//   no partial-line RMW (R7 invariant preserved).
// R chosen host-side from ws_size (8/4/2/1); R=1 == R8 exactly.
// Also: fast transcendentals (__expf/__fdividef) in the finisher, and
// float4 LDS reads in the matvec (128 -> 32 LDS ops).

typedef unsigned int u32;
typedef unsigned long long u64;

constexpr int kH     = 1024;
constexpr int kT     = 2048;
constexpr int kIN    = 5;
constexpr int kOUT   = 9;
constexpr int kNWG   = 64;
constexpr int kBLOCK = 512;

__device__ __forceinline__ float sigm_(float v) {
  return __fdividef(1.0f, 1.0f + __expf(-v));
}
__device__ __forceinline__ float tanh_(float v) {
  return 1.0f - __fdividef(2.0f, __expf(2.0f * v) + 1.0f);
}
__device__ __forceinline__ u32 bf16_rne(float f) {
  u32 b = __float_as_uint(f);
  return (b + 0x7FFFu + ((b >> 16) & 1u)) >> 16;
}
__device__ __forceinline__ float lo_f(u32 p) { return __uint_as_float(p << 16); }
__device__ __forceinline__ float hi_f(u32 p) { return __uint_as_float(p & 0xFFFF0000u); }

// One poll sample: 8B/lane, wave-coalesced 512B, LLC-coherent.
__device__ __forceinline__ u64 poll1(const u64* p) {
  u64 a;
  asm volatile(
      "global_load_dwordx2 %0, %1, off sc0 sc1\n\t"
      "s_waitcnt vmcnt(0)"
      : "=v"(a) : "v"(p) : "memory");
  return a;
}

// Epilogue-only: 8 x 8B at 512B stride (atoms lane + 64m), one drain.
__device__ __forceinline__ void poll8(const u64* p, u64& a0, u64& a1, u64& a2,
                                      u64& a3, u64& a4, u64& a5, u64& a6,
                                      u64& a7) {
  asm volatile(
      "global_load_dwordx2 %0, %8, off sc0 sc1\n\t"
      "global_load_dwordx2 %1, %8, off offset:512 sc0 sc1\n\t"
      "global_load_dwordx2 %2, %8, off offset:1024 sc0 sc1\n\t"
      "global_load_dwordx2 %3, %8, off offset:1536 sc0 sc1\n\t"
      "global_load_dwordx2 %4, %8, off offset:2048 sc0 sc1\n\t"
      "global_load_dwordx2 %5, %8, off offset:2560 sc0 sc1\n\t"
      "global_load_dwordx2 %6, %8, off offset:3072 sc0 sc1\n\t"
      "global_load_dwordx2 %7, %8, off offset:3584 sc0 sc1\n\t"
      "s_waitcnt vmcnt(0)"
      : "=&v"(a0), "=&v"(a1), "=&v"(a2), "=&v"(a3),
        "=&v"(a4), "=&v"(a5), "=&v"(a6), "=&v"(a7)
      : "v"(p)
      : "memory");
}

__global__ __launch_bounds__(kBLOCK, 2) void lstm_v9(
    const float* __restrict__ x,     // [T,1,IN]
    const float* __restrict__ w_ih,  // [4H,IN]
    const float* __restrict__ w_hh,  // [4H,H]
    const float* __restrict__ b_ih,  // [4H]
    const float* __restrict__ b_hh,  // [4H]
    const float* __restrict__ w_out, // [OUT,H]
    const float* __restrict__ b_out, // [OUT]
    float* __restrict__ out,         // [OUT]
    u64* __restrict__ ring,          // ring[4][R][512]
    u32 slotStride,                  // R*512 (u64 units)
    u32 repMask,                     // R-1
    u32 pubLanes) {                  // 8*R
  const int pid  = blockIdx.x;
  const int tid  = threadIdx.x;
  const int w    = tid >> 6;
  const int lane = tid & 63;

  __shared__ float x_lds[kT * kIN];           // 40 KiB
  __shared__ __align__(16) float h_lds[kH];   // 4 KiB; wave w owns [128w,+128)
  __shared__ float pacc[2][7][64];            // partials, dbuf by t&1
  __shared__ int   gcnt;                      // monotonic counter

  for (int i = tid; i < kT * kIN; i += kBLOCK) x_lds[i] = x[i];
  if (tid == 0) gcnt = 0;

  // Lane l owns gate-row l: gate g = l>>4 ([i,f,g,o]), j = l&15.
  const int grow = (lane >> 4) * kH + pid * 16 + (lane & 15);
  const int cb   = 128 * w;  // this wave's h-column slice base

  float wreg[128];
  {
    const float* sp = w_hh + (size_t)grow * kH + cb;
#pragma unroll
    for (int m = 0; m < 128; m += 4) {
      const float4 v4 = *(const float4*)(sp + m);
      wreg[m] = v4.x; wreg[m + 1] = v4.y; wreg[m + 2] = v4.z; wreg[m + 3] = v4.w;
    }
  }
  float wihr[kIN];
#pragma unroll
  for (int k = 0; k < kIN; ++k) wihr[k] = w_ih[grow * kIN + k];
  const float biasr = b_ih[grow] + b_hh[grow];

  const u32 myRep = (u32)pid & repMask;
  float cst = 0.0f;  // wave7: cell state for j = lane&15
  __syncthreads();   // x_lds + gcnt ready — only barrier in the kernel

  for (int t = 0; t < kT; ++t) {
    // gx for row `lane` — before the wait
    float gx = biasr;
#pragma unroll
    for (int k = 0; k < kIN; ++k) gx = fmaf(wihr[k], x_lds[t * kIN + k], gx);

    // ---- poll own slice in own replica: atom 64w+lane ----
    const u64* pb = ring + (size_t)(t & 3) * slotStride + myRep * 512 +
                    64 * w + lane;
    u64 a;
    do {
      a = poll1(pb);
    } while (!__all((u32)(a >> 32) == (u32)t));

    // unpack into this wave's private h segment: atom -> cols {cb+2l, +1}
    const u32 d = (u32)a;
    *(float2*)&h_lds[cb + 2 * lane] = make_float2(lo_f(d), hi_f(d));

    // ---- partial matvec: row `lane` x cols [cb, cb+128), float4 reads ----
    float acc0 = 0.0f, acc1 = 0.0f, acc2 = 0.0f, acc3 = 0.0f;
#pragma unroll
    for (int m = 0; m < 128; m += 4) {
      const float4 h4 = *(const float4*)&h_lds[cb + m];
      acc0 = fmaf(wreg[m + 0], h4.x, acc0);
      acc1 = fmaf(wreg[m + 1], h4.y, acc1);
      acc2 = fmaf(wreg[m + 2], h4.z, acc2);
      acc3 = fmaf(wreg[m + 3], h4.w, acc3);
    }
    const float part = (acc0 + acc1) + (acc2 + acc3);

    if (w < 7) {
      pacc[t & 1][w][lane] = part;
      if (lane == 0)
        __hip_atomic_fetch_add(&gcnt, 1, __ATOMIC_RELEASE,
                               __HIP_MEMORY_SCOPE_WORKGROUP);
    } else {
      // ---- finisher ----
      while (__hip_atomic_load(&gcnt, __ATOMIC_ACQUIRE,
                               __HIP_MEMORY_SCOPE_WORKGROUP) < 7 * (t + 1)) { }
      float gtot = part + gx;
#pragma unroll
      for (int w2 = 0; w2 < 7; ++w2) gtot += pacc[t & 1][w2][lane];

      const int gate = lane >> 4;        // [i,f,g,o]; g -> tanh
      const float u = (gate == 2) ? 2.0f * gtot : gtot;
      float n = sigm_(u);
      n = (gate == 2) ? (2.0f * n - 1.0f) : n;

      const int j = lane & 15;
      const float ni = __shfl(n, j);
      const float nf = __shfl(n, 16 + j);
      const float ng = __shfl(n, 32 + j);
      const float no = __shfl(n, 48 + j);
      cst = nf * cst + ni * ng;
      const float hval = no * tanh_(cst);

      // publish to ALL replicas with one wave store:
      // lane k -> replica k>>3, atom pid*8 + (k&7): 8 disjoint full lines.
      const int al = lane & 7;
      const float ph0 = __shfl(hval, 2 * al);      // j = 2*al
      const float ph1 = __shfl(hval, 2 * al + 1);  // j = 2*al+1
      if (lane < (int)pubLanes) {
        const u64 atom = ((u64)(u32)(t + 1) << 32) |
                         (u64)(bf16_rne(ph0) | (bf16_rne(ph1) << 16));
        __hip_atomic_store(ring + (size_t)((t + 1) & 3) * slotStride +
                               (size_t)(lane >> 3) * 512 + pid * 8 + al,
                           atom, __ATOMIC_RELAXED, __HIP_MEMORY_SCOPE_AGENT);
      }
    }
  }

  // ---- epilogue: tanh -> 9x1024 matvec -> log_softmax (WG0 wave0) ----
  if (pid == 0 && w == 0) {
    const u64* pb = ring + (size_t)(kT & 3) * slotStride + lane;  // replica 0
    u64 a0, a1, a2, a3, a4, a5, a6, a7;
    bool ok;
    do {
      poll8(pb, a0, a1, a2, a3, a4, a5, a6, a7);
      ok = ((u32)(a0 >> 32) == (u32)kT) & ((u32)(a1 >> 32) == (u32)kT) &
           ((u32)(a2 >> 32) == (u32)kT) & ((u32)(a3 >> 32) == (u32)kT) &
           ((u32)(a4 >> 32) == (u32)kT) & ((u32)(a5 >> 32) == (u32)kT) &
           ((u32)(a6 >> 32) == (u32)kT) & ((u32)(a7 >> 32) == (u32)kT);
    } while (!__all(ok));

    u64 av[8] = {a0, a1, a2, a3, a4, a5, a6, a7};
    float logits[kOUT];
#pragma unroll
    for (int r = 0; r < kOUT; ++r) logits[r] = 0.0f;
#pragma unroll
    for (int m = 0; m < 8; ++m) {
      const u32 d = (u32)av[m];
      const float z0 = tanhf(lo_f(d));
      const float z1 = tanhf(hi_f(d));
      const int col = 2 * lane + 128 * m;
#pragma unroll
      for (int r = 0; r < kOUT; ++r) {
        const float2 wv = *(const float2*)(w_out + (size_t)r * kH + col);
        logits[r] = fmaf(wv.x, z0, fmaf(wv.y, z1, logits[r]));
      }
    }
#pragma unroll
    for (int r = 0; r < kOUT; ++r) {
#pragma unroll
      for (int off = 32; off; off >>= 1)
        logits[r] += __shfl_xor(logits[r], off);
      logits[r] += b_out[r];
    }
    if (lane == 0) {
      float m = logits[0];
#pragma unroll
      for (int r = 1; r < kOUT; ++r) m = fmaxf(m, logits[r]);
      float s = 0.0f;
#pragma unroll
      for (int r = 0; r < kOUT; ++r) s += expf(logits[r] - m);
      const float lse = m + logf(s);
#pragma unroll
      for (int r = 0; r < kOUT; ++r) out[r] = logits[r] - lse;
    }
  }
}

extern "C" void kernel_launch(void* const* d_in, const int* in_sizes, int n_in,
                              void* d_out, int out_size, void* d_ws, size_t ws_size,
                              hipStream_t stream) {
  const float* x     = (const float*)d_in[0];
  const float* w_ih  = (const float*)d_in[1];
  const float* w_hh  = (const float*)d_in[2];
  const float* b_ih  = (const float*)d_in[3];
  const float* b_hh  = (const float*)d_in[4];
  const float* w_out = (const float*)d_in[5];
  const float* b_out = (const float*)d_in[6];
  float* out  = (float*)d_out;
  u64*   ring = (u64*)d_ws;

  // Replica count from workspace budget: 4 slots x R x 4KB.
  int R = 1;
  if      (ws_size >= 4ull * 8 * 4096) R = 8;
  else if (ws_size >= 4ull * 4 * 4096) R = 4;
  else if (ws_size >= 4ull * 2 * 4096) R = 2;
  const u32 slotStride = (u32)(R * 512);  // u64 units

  // Zero the whole ring each call (slot0 tag0/h0 = 0; clear stale tags).
  hipMemsetAsync(d_ws, 0, (size_t)4 * slotStride * sizeof(u64), stream);

  lstm_v9<<<kNWG, kBLOCK, 0, stream>>>(x, w_ih, w_hh, b_ih, b_hh,
                                       w_out, b_out, out, ring,
                                       slotStride, (u32)(R - 1), (u32)(8 * R));
}